// Round 12
// baseline (275.749 us; speedup 1.0000x reference)
//
#include <hip/hip_runtime.h>

typedef unsigned short u16;
typedef __attribute__((ext_vector_type(8))) short s16x8;   // 8 x bf16 frag (verified form)
typedef __attribute__((ext_vector_type(4))) float floatx4;

// xt (per batch): [cg=16][row=66][col=66][c32=32] bf16, spatial-padded NCHW32c
// SWIZZLED: within each 64B (row,col) channel-group, 16B slot ^= (col>>1)&3
#define XT_ROWELEMS 2112                 // 66*32
#define XT_CGELEMS  139392               // 66*66*32
#define XT_PB       4460544ull           // 16*66*66*32*2 bytes per batch
// wmod (per batch): [t=9][cg=16][o512=512][c32=32] bf16  (o512 contiguous)
// SWIZZLED: within each 64B o-row, c32 index ^= ((o>>1)&3)<<3
#define WM_ELEMS    2359296ull           // 9*16*512*32 elems per batch
#define WM_PB       4718592ull           // bytes per batch

// async global->LDS DMA, 16B per lane; lds dest = wave-uniform base + lane*16
#define GLDS(gp, lp) __builtin_amdgcn_global_load_lds(                      \
    (const __attribute__((address_space(1))) void*)(gp),                    \
    (__attribute__((address_space(3))) void*)(lp), 16, 0, 0)

// counted vmcnt (memory clobber: LDS reads cannot hoist above)
#define WAITVM(N) asm volatile("s_waitcnt vmcnt(" #N ")" ::: "memory")

__device__ __forceinline__ u16 f2bf(float f) {
  union { float f; unsigned u; } x; x.f = f;
  unsigned r = x.u + 0x7fffu + ((x.u >> 16) & 1u);
  return (u16)(r >> 16);
}

// ---------------- prep unit bodies (byte-identical layouts; verified R6-R11) ----------------
__device__ __forceinline__ void transpose_unit(
    char* smraw, const float* __restrict__ fm, u16* __restrict__ xt, int ti, int tid)
{
  u16* sm16 = (u16*)smraw;                      // [x=64][ci=32] pad 40
  const int y = ti & 63, cgi = (ti >> 6) & 15, bl = ti >> 10;
  const float* src = fm + (((size_t)bl * 512 + cgi * 32) * 64 + y) * 64;
  const int x4 = (tid & 15) * 4;
#pragma unroll
  for (int it = 0; it < 2; ++it) {
    int ci = (tid >> 4) + it * 16;
    float4 v = *(const float4*)&src[(size_t)ci * 4096 + x4];   // 16B/lane coalesced
    sm16[(x4 + 0) * 40 + ci] = f2bf(v.x);
    sm16[(x4 + 1) * 40 + ci] = f2bf(v.y);
    sm16[(x4 + 2) * 40 + ci] = f2bf(v.z);
    sm16[(x4 + 3) * 40 + ci] = f2bf(v.w);
  }

  u16* cgbase = xt + (size_t)(bl * 16 + cgi) * XT_CGELEMS;
  const uint4 z = {0u, 0u, 0u, 0u};
  u16* rowb = cgbase + (size_t)(y + 1) * XT_ROWELEMS;
  if (tid < 4)              ((uint4*)rowb)[tid] = z;                  // col 0
  else if (tid < 8)         ((uint4*)(rowb + 65 * 32))[tid - 4] = z;  // col 65
  if (y == 0)  for (int i = tid; i < 264; i += 256) ((uint4*)cgbase)[i] = z;
  if (y == 63) for (int i = tid; i < 264; i += 256) ((uint4*)(cgbase + 65 * XT_ROWELEMS))[i] = z;

  __syncthreads();
  const int x = tid >> 2;
  uint4 u = *(const uint4*)&sm16[x * 40 + (tid & 3) * 8];       // one ds_read_b128
  const int col = 1 + x;
  const int slot = (tid & 3) ^ ((col >> 1) & 3);                // pre-swizzle
  ((uint4*)rowb)[col * 4 + slot] = u;
}

__device__ __forceinline__ void modulate_unit(
    char* smraw, const float* __restrict__ w, const float* __restrict__ style,
    u16* __restrict__ wm, int mi, int tid)
{
  float* sv = (float*)smraw;                    // 4608 floats
  float* red = (float*)(smraw + 18432);         // 4 floats
  const int o = mi & 511, bl = mi >> 9;
  const float gain = 0.014731391f;              // 1/sqrt(512*9)
  const float* wo = w + (size_t)o * 4608;       // flat idx = ci*9 + t
  const float* st = style + (size_t)bl * 512;
  float ss = 0.f;
#pragma unroll
  for (int j = 0; j < 5; ++j) {                 // 1152 float4 slots over 256 thr
    int s4 = j * 256 + tid;
    if (s4 < 1152) {
      float4 v = *(const float4*)&wo[s4 * 4];   // 16B/lane coalesced
      int i0 = s4 * 4;
      int c0 = i0 / 9, rem = i0 - c0 * 9;       // ci of v.x
      float sa = st[c0];
      float sb = st[c0 < 511 ? c0 + 1 : 511];   // clamp: unused when c0==511
      float w0 = v.x * gain * sa;               // rem+0 < 9 always
      float w1 = v.y * gain * (rem + 1 >= 9 ? sb : sa);
      float w2 = v.z * gain * (rem + 2 >= 9 ? sb : sa);
      float w3 = v.w * gain * (rem + 3 >= 9 ? sb : sa);
      floatx4 wv = {w0, w1, w2, w3};
      ((floatx4*)sv)[s4] = wv;                  // ds_write_b128
      ss += w0 * w0 + w1 * w1 + w2 * w2 + w3 * w3;
    }
  }
#pragma unroll
  for (int off = 32; off > 0; off >>= 1) ss += __shfl_down(ss, off, 64);
  if ((tid & 63) == 0) red[tid >> 6] = ss;
  __syncthreads();
  float sinv = rsqrtf(red[0] + red[1] + red[2] + red[3] + 1e-8f);
  const int axor = ((o >> 1) & 3) << 3;         // pre-swizzle for conv A-reads
  u16* base = wm + (size_t)bl * WM_ELEMS + (size_t)o * 32;
  const int c0 = tid * 2;                       // even -> XOR keeps pair adjacent
  const int pos = (c0 & 31) ^ axor;             // even (axor has no bit0)
#pragma unroll
  for (int t = 0; t < 9; ++t) {                 // 9 paired u32 stores
    unsigned lo = f2bf(sv[c0 * 9 + t] * sinv);
    unsigned hi = f2bf(sv[(c0 + 1) * 9 + t] * sinv);
    *(unsigned*)(base + ((size_t)(t * 16 + (c0 >> 5))) * 16384 + pos) = lo | (hi << 16);
  }
}

// ---------------- fused producer dispatch (verified; prep ~24 us, near roofline) ----------------
__global__ __launch_bounds__(256) void prep_fused(
    const float* __restrict__ fm, const float* __restrict__ w,
    const float* __restrict__ style, u16* __restrict__ xt,
    u16* __restrict__ wm, int b0)
{
  __shared__ __align__(16) char smraw[18448];
  const int bid = blockIdx.x;
  const int g = bid / 3, rrole = bid - g * 3;
  const int tid = threadIdx.x;
  if (rrole < 2) {
    const int ti0 = g * 2 + rrole;
    const int y = ti0 & 63, cgi = (ti0 >> 6) & 15, bl = ti0 >> 10;
    transpose_unit(smraw, fm + (size_t)b0 * 512 * 4096,
                   xt, (bl << 10) | (cgi << 6) | y, tid);
  } else {
    const int o = g & 511, bl = g >> 9;
    modulate_unit(smraw, w, style + (size_t)b0 * 512, wm, (bl << 9) | o, tid);
  }
}

// ---------------- conv: R11 counted-vmcnt structure + uniform WAITVM(4) ----------------
// 256x128 C tile, 256 threads = 4 waves, wave tile 128x64, 16x16x32 MFMA. Reads,
// MFMA, epilogue byte-identical to R6/R11 (verified). R11 change kept: counted
// vmcnt + raw barrier per step, A tri-buffered depth-2. R12 fix: t==8 is
// restructured as {read frags -> lgkmcnt(0) -> barrier -> stage_b(cg+1) ->
// stage_a(s+2) -> MFMA}, putting B OLDER than A(s+2) in the FIFO. Then every
// step top is a uniform WAITVM(4): at t==0 it confirms A(s+1) AND B(cg) while
// keeping A(s+2) in flight — the 16x full vmcnt(0) drains of R11 are gone
// (only the final step s==143 drains to 0). Per-wave FIFO verified for
// prologue / steady / cg-cross / tail; wave0's 5th B load is also covered by
// WAITVM(4) (drain-to-4 retires all 5).
__global__ __launch_bounds__(256, 2) void conv_mfma(
    const u16* __restrict__ Wmod, const u16* __restrict__ xt,
    float* __restrict__ out, int b0, int nb)
{
  const int id = blockIdx.x;
  const int bl = id % nb;                           // same batch -> same XCD (round robin)
  const int rest = id / nb;
  const int og = rest & 1, p_blk = rest >> 1;       // og: 256-row M chunk; p_blk: 128 px
  const int tid = threadIdx.x;
  const int lane = tid & 63, wave = tid >> 6;
  const int wm_off = (wave & 1) * 128, wn_off = (wave >> 1) * 64;
  const int l15 = lane & 15, quad = lane >> 4;

  __shared__ __align__(16) u16 As[3][8192];         // 3 x 16 KB A k-slices (tri-buffer)
  __shared__ __align__(16) u16 Bs[8448];            // [r4][col66][c32] = 16896 B

  const int y0 = p_blk * 2;
  const size_t xt_base = ((size_t)(bl * 16) * XT_CGELEMS) + (size_t)y0 * XT_ROWELEMS;
  const size_t w_base = (size_t)bl * WM_ELEMS + (size_t)og * (256 * 32);

  auto stage_b = [&](int cgi) {                     // 16896 B contiguous, async
    const char* g = (const char*)(xt + xt_base + (size_t)cgi * XT_CGELEMS);
    for (int r = wave; r < 16; r += 4)              // 4 GLDS/wave
      GLDS(g + r * 1024 + lane * 16, (char*)Bs + r * 1024);
    if (wave == 0 && lane < 32)                     // 512 B tail (wave0: 5th load)
      GLDS(g + 16384 + lane * 16, (char*)Bs + 16384);
  };
  auto stage_a = [&](int t, int cgi, int buf) {     // 16 KB contiguous, 4 GLDS/wave
    const char* g = (const char*)(Wmod + w_base + (size_t)(t * 16 + cgi) * 16384);
    for (int r = wave; r < 16; r += 4)
      GLDS(g + r * 1024 + lane * 16, (char*)As[buf] + r * 1024);
  };

  // loop-invariant swizzled fragment addresses (verified; conflicts = 0)
  int aoff[8];
#pragma unroll
  for (int mt = 0; mt < 8; ++mt) {
    int row = wm_off + mt * 16 + l15;               // local o-row; global o = og*256+row
    aoff[mt] = row * 32 + ((quad ^ ((row >> 1) & 3)) << 3);
  }
  int pr[4], pc[4];
#pragma unroll
  for (int nt = 0; nt < 4; ++nt) {
    int p = wn_off + nt * 16 + l15;
    pr[nt] = p >> 6; pc[nt] = p & 63;
  }

  floatx4 acc[8][4];
  const floatx4 zf = {0.f, 0.f, 0.f, 0.f};
#pragma unroll
  for (int mt = 0; mt < 8; ++mt)
#pragma unroll
    for (int nt = 0; nt < 4; ++nt) acc[mt][nt] = zf;

  // prologue: B(0), A(0)->buf0, A(1)->buf1; WAITVM(4) drains B(0)+A(0), keeps A(1)
  stage_b(0);
  stage_a(0, 0, 0);
  stage_a(1, 0, 1);
  WAITVM(4);
  __builtin_amdgcn_s_barrier();
  __builtin_amdgcn_sched_barrier(0);

#pragma unroll 1
  for (int cgi = 0; cgi < 16; ++cgi) {
#pragma unroll
    for (int t = 0; t < 9; ++t) {
      const int cur = t % 3;                        // s%3 == t%3 (9 ≡ 0 mod 3)
      const int nx2 = (t + 2) % 3;                  // buffer for A(s+2)
      // ---- top of step: counted drain + rendezvous (s==0 covered by prologue) ----
      if (cgi > 0 || t > 0) {
        if (cgi == 15 && t == 8) { WAITVM(0); }     // final step: only A(143) outstanding
        else                     { WAITVM(4); }     // A(s) [+B at t==0] done; newest 4 fly
        __builtin_amdgcn_s_barrier();
        __builtin_amdgcn_sched_barrier(0);
      }
      // ---- t<8: issue A(s+2) prefetch now (WAR-safe: its readers at s-1 retired
      //      their ds_reads before the top-of-s barrier) ----
      if (t < 8 && !(cgi == 15 && t == 7)) {
        int t2 = t + 2, cg2 = cgi;
        if (t2 >= 9) { t2 -= 9; ++cg2; }
        stage_a(t2, cg2, nx2);
      }

      const int ky = t / 3, kx = t - ky * 3;
      s16x8 afr[8], bfr[4];
      const u16* Ab = As[cur];
#pragma unroll
      for (int nt = 0; nt < 4; ++nt) {              // B[n=lane&15][k=quad*8+j], swizzled
        int r = pr[nt] + ky, c = pc[nt] + kx;
        bfr[nt] = *(const s16x8*)&Bs[(r * 66 + c) * 32 + ((quad ^ ((c >> 1) & 3)) << 3)];
      }
#pragma unroll
      for (int mt = 0; mt < 8; ++mt)                // A[m=lane&15][k=quad*8+j], swizzled
        afr[mt] = *(const s16x8*)&Ab[aoff[mt]];

      if (t == 8) {
        // all frag reads into regs -> retire -> rendezvous -> restage B (older in
        // FIFO) + prefetch A(s+2); both then fly under this step's MFMA cluster.
        asm volatile("s_waitcnt lgkmcnt(0)" ::: "memory");
        __builtin_amdgcn_sched_barrier(0);
        __builtin_amdgcn_s_barrier();
        if (cgi < 15) {
          stage_b(cgi + 1);                         // B first (confirmed by next WAITVM(4))
          stage_a(1, cgi + 1, nx2);                 // A(s+2) = (cg+1, t=1); buf nx2 = 1
        }
      }

#pragma unroll
      for (int mt = 0; mt < 8; ++mt)
#pragma unroll
        for (int nt = 0; nt < 4; ++nt)
          acc[mt][nt] = __builtin_amdgcn_mfma_f32_16x16x32_bf16(
              afr[mt], bfr[nt], acc[mt][nt], 0, 0, 0);
    }
  }

  // epilogue: C/D layout col=lane&15, row=quad*4+reg (m89-verified)
  float* outp = out + ((size_t)(b0 + bl) * 512 + og * 256) * 4096 + p_blk * 128;
#pragma unroll
  for (int mt = 0; mt < 8; ++mt)
#pragma unroll
    for (int nt = 0; nt < 4; ++nt) {
      int n = wn_off + nt * 16 + l15;
#pragma unroll
      for (int r = 0; r < 4; ++r) {
        int m = wm_off + mt * 16 + quad * 4 + r;
        outp[(size_t)m * 4096 + n] = acc[mt][nt][r];
      }
    }
}

// ---------------- fallback: zero-workspace direct conv (known-PASS) ----------------
__global__ __launch_bounds__(256) void conv_direct(
    const float* __restrict__ fm, const float* __restrict__ style,
    const float* __restrict__ w, float* __restrict__ out)
{
  const int o = blockIdx.x, b = blockIdx.y, tid = threadIdx.x;
  __shared__ float swm[4608];
  __shared__ float red[4];
  const float gain = 0.014731391f;
  const float* wo = w + (size_t)o * 4608;
  const float* st = style + (size_t)b * 512;
  float ss = 0.f;
#pragma unroll
  for (int j = 0; j < 18; ++j) {
    int idx = j * 256 + tid;
    float v = wo[idx] * gain * st[idx / 9];
    swm[idx] = v;
    ss += v * v;
  }
#pragma unroll
  for (int off = 32; off > 0; off >>= 1) ss += __shfl_down(ss, off, 64);
  if ((tid & 63) == 0) red[tid >> 6] = ss;
  __syncthreads();
  const float sinv = rsqrtf(red[0] + red[1] + red[2] + red[3] + 1e-8f);

  const int y = tid >> 2, x0 = (tid & 3) * 16;
  float acc[16];
#pragma unroll
  for (int i = 0; i < 16; ++i) acc[i] = 0.f;
  const float* fb = fm + (size_t)b * 512 * 4096;
  for (int ci = 0; ci < 512; ++ci) {
    const float* fc = fb + (size_t)ci * 4096;
    const float* wr = swm + ci * 9;
#pragma unroll
    for (int ky = 0; ky < 3; ++ky) {
      int yy = y + ky - 1;
      if (yy < 0 || yy > 63) continue;
      const float* frow = fc + yy * 64;
#pragma unroll
      for (int kx = 0; kx < 3; ++kx) {
        float wv = wr[ky * 3 + kx];
#pragma unroll
        for (int i = 0; i < 16; ++i) {
          int xx = x0 + i + kx - 1;
          float xv = (xx >= 0 && xx < 64) ? frow[xx] : 0.f;
          acc[i] += wv * xv;
        }
      }
    }
  }
  float* op = out + ((size_t)b * 512 + o) * 4096 + y * 64 + x0;
#pragma unroll
  for (int i = 0; i < 16; ++i) op[i] = acc[i] * sinv;
}

extern "C" void kernel_launch(void* const* d_in, const int* in_sizes, int n_in,
                              void* d_out, int out_size, void* d_ws, size_t ws_size,
                              hipStream_t stream) {
  const float* fm = (const float*)d_in[0];     // (8,512,64,64) fp32
  const float* style = (const float*)d_in[1];  // (8,512) fp32
  const float* w = (const float*)d_in[2];      // (512,512,3,3) fp32
  float* out = (float*)d_out;                  // (8,512,64,64) fp32

  if (ws_size < XT_PB + WM_PB) {               // workspace too small: direct path
    conv_direct<<<dim3(512, 8), 256, 0, stream>>>(fm, style, w, out);
    return;
  }
  int nb = 8;
  while (nb > 1 && (size_t)nb * (XT_PB + WM_PB) > ws_size) nb >>= 1;

  u16* xt = (u16*)d_ws;
  u16* wmod = (u16*)((char*)d_ws + (size_t)nb * XT_PB);

  for (int b0 = 0; b0 < 8; b0 += nb) {
    prep_fused<<<dim3(1536 * nb), 256, 0, stream>>>(fm, w, style, xt, wmod, b0);
    conv_mfma<<<dim3(64 * nb), 256, 0, stream>>>(wmod, xt, out, b0, nb);
  }
}

// Round 13
// 270.485 us; speedup vs baseline: 1.0195x; 1.0195x over previous
//
#include <hip/hip_runtime.h>

typedef unsigned short u16;
typedef __attribute__((ext_vector_type(8))) short s16x8;   // 8 x bf16 frag (verified form)
typedef __attribute__((ext_vector_type(4))) float floatx4;

// xt (per batch): [cg=16][row=66][col=66][c32=32] bf16, spatial-padded NCHW32c
// SWIZZLED: within each 64B (row,col) channel-group, 16B slot ^= (col>>1)&3
#define XT_ROWELEMS 2112                 // 66*32
#define XT_CGELEMS  139392               // 66*66*32
#define XT_PB       4460544ull           // 16*66*66*32*2 bytes per batch
// wmod (per batch): [t=9][cg=16][o512=512][c32=32] bf16  (o512 contiguous)
// SWIZZLED: within each 64B o-row, c32 index ^= ((o>>1)&3)<<3
#define WM_ELEMS    2359296ull           // 9*16*512*32 elems per batch
#define WM_PB       4718592ull           // bytes per batch

// async global->LDS DMA, 16B per lane; lds dest = wave-uniform base + lane*16
#define GLDS(gp, lp) __builtin_amdgcn_global_load_lds(                      \
    (const __attribute__((address_space(1))) void*)(gp),                    \
    (__attribute__((address_space(3))) void*)(lp), 16, 0, 0)

// counted vmcnt (memory clobber: LDS reads cannot hoist above)
#define WAITVM(N) asm volatile("s_waitcnt vmcnt(" #N ")" ::: "memory")

__device__ __forceinline__ u16 f2bf(float f) {
  union { float f; unsigned u; } x; x.f = f;
  unsigned r = x.u + 0x7fffu + ((x.u >> 16) & 1u);
  return (u16)(r >> 16);
}

// ---------------- prep unit bodies (byte-identical layouts; verified R6-R12) ----------------
__device__ __forceinline__ void transpose_unit(
    char* smraw, const float* __restrict__ fm, u16* __restrict__ xt, int ti, int tid)
{
  u16* sm16 = (u16*)smraw;                      // [x=64][ci=32] pad 40
  const int y = ti & 63, cgi = (ti >> 6) & 15, bl = ti >> 10;
  const float* src = fm + (((size_t)bl * 512 + cgi * 32) * 64 + y) * 64;
  const int x4 = (tid & 15) * 4;
#pragma unroll
  for (int it = 0; it < 2; ++it) {
    int ci = (tid >> 4) + it * 16;
    float4 v = *(const float4*)&src[(size_t)ci * 4096 + x4];   // 16B/lane coalesced
    sm16[(x4 + 0) * 40 + ci] = f2bf(v.x);
    sm16[(x4 + 1) * 40 + ci] = f2bf(v.y);
    sm16[(x4 + 2) * 40 + ci] = f2bf(v.z);
    sm16[(x4 + 3) * 40 + ci] = f2bf(v.w);
  }

  u16* cgbase = xt + (size_t)(bl * 16 + cgi) * XT_CGELEMS;
  const uint4 z = {0u, 0u, 0u, 0u};
  u16* rowb = cgbase + (size_t)(y + 1) * XT_ROWELEMS;
  if (tid < 4)              ((uint4*)rowb)[tid] = z;                  // col 0
  else if (tid < 8)         ((uint4*)(rowb + 65 * 32))[tid - 4] = z;  // col 65
  if (y == 0)  for (int i = tid; i < 264; i += 256) ((uint4*)cgbase)[i] = z;
  if (y == 63) for (int i = tid; i < 264; i += 256) ((uint4*)(cgbase + 65 * XT_ROWELEMS))[i] = z;

  __syncthreads();
  const int x = tid >> 2;
  uint4 u = *(const uint4*)&sm16[x * 40 + (tid & 3) * 8];       // one ds_read_b128
  const int col = 1 + x;
  const int slot = (tid & 3) ^ ((col >> 1) & 3);                // pre-swizzle
  ((uint4*)rowb)[col * 4 + slot] = u;
}

__device__ __forceinline__ void modulate_unit(
    char* smraw, const float* __restrict__ w, const float* __restrict__ style,
    u16* __restrict__ wm, int mi, int tid)
{
  float* sv = (float*)smraw;                    // 4608 floats
  float* red = (float*)(smraw + 18432);         // 4 floats
  const int o = mi & 511, bl = mi >> 9;
  const float gain = 0.014731391f;              // 1/sqrt(512*9)
  const float* wo = w + (size_t)o * 4608;       // flat idx = ci*9 + t
  const float* st = style + (size_t)bl * 512;
  float ss = 0.f;
#pragma unroll
  for (int j = 0; j < 5; ++j) {                 // 1152 float4 slots over 256 thr
    int s4 = j * 256 + tid;
    if (s4 < 1152) {
      float4 v = *(const float4*)&wo[s4 * 4];   // 16B/lane coalesced
      int i0 = s4 * 4;
      int c0 = i0 / 9, rem = i0 - c0 * 9;       // ci of v.x
      float sa = st[c0];
      float sb = st[c0 < 511 ? c0 + 1 : 511];   // clamp: unused when c0==511
      float w0 = v.x * gain * sa;               // rem+0 < 9 always
      float w1 = v.y * gain * (rem + 1 >= 9 ? sb : sa);
      float w2 = v.z * gain * (rem + 2 >= 9 ? sb : sa);
      float w3 = v.w * gain * (rem + 3 >= 9 ? sb : sa);
      floatx4 wv = {w0, w1, w2, w3};
      ((floatx4*)sv)[s4] = wv;                  // ds_write_b128
      ss += w0 * w0 + w1 * w1 + w2 * w2 + w3 * w3;
    }
  }
#pragma unroll
  for (int off = 32; off > 0; off >>= 1) ss += __shfl_down(ss, off, 64);
  if ((tid & 63) == 0) red[tid >> 6] = ss;
  __syncthreads();
  float sinv = rsqrtf(red[0] + red[1] + red[2] + red[3] + 1e-8f);
  const int axor = ((o >> 1) & 3) << 3;         // pre-swizzle for conv A-reads
  u16* base = wm + (size_t)bl * WM_ELEMS + (size_t)o * 32;
  const int c0 = tid * 2;                       // even -> XOR keeps pair adjacent
  const int pos = (c0 & 31) ^ axor;             // even (axor has no bit0)
#pragma unroll
  for (int t = 0; t < 9; ++t) {                 // 9 paired u32 stores
    unsigned lo = f2bf(sv[c0 * 9 + t] * sinv);
    unsigned hi = f2bf(sv[(c0 + 1) * 9 + t] * sinv);
    *(unsigned*)(base + ((size_t)(t * 16 + (c0 >> 5))) * 16384 + pos) = lo | (hi << 16);
  }
}

// ---------------- fused producer dispatch (verified; prep ~24 us, near roofline) ----------------
__global__ __launch_bounds__(256) void prep_fused(
    const float* __restrict__ fm, const float* __restrict__ w,
    const float* __restrict__ style, u16* __restrict__ xt,
    u16* __restrict__ wm, int b0)
{
  __shared__ __align__(16) char smraw[18448];
  const int bid = blockIdx.x;
  const int g = bid / 3, rrole = bid - g * 3;
  const int tid = threadIdx.x;
  if (rrole < 2) {
    const int ti0 = g * 2 + rrole;
    const int y = ti0 & 63, cgi = (ti0 >> 6) & 15, bl = ti0 >> 10;
    transpose_unit(smraw, fm + (size_t)b0 * 512 * 4096,
                   xt, (bl << 10) | (cgi << 6) | y, tid);
  } else {
    const int o = g & 511, bl = g >> 9;
    modulate_unit(smraw, w, style + (size_t)b0 * 512, wm, (bl << 9) | o, tid);
  }
}

// ---------------- conv: R11 counted-vmcnt structure (best verified: 158 us), s==1 fixed ----------------
// 256x128 C tile, 256 threads = 4 waves, wave tile 128x64, 16x16x32 MFMA — reads,
// MFMA, epilogue byte-identical to verified R6. Counted vmcnt + raw barrier per
// step; A TRI-buffered depth-2 (stage A(s+2) after the top barrier; WAITVM(4)
// leaves A(s+1) in flight at 127/144 steps). B single-buffered, restaged behind a
// plain barrier at cg boundaries, confirmed by WAITVM(0) at t==0 (B is newest in
// FIFO there — the only full drains, 16x). s==1 fixed vs R11: FIFO = [A(1)x4,
// A(2)x4], WAITVM(4) confirms A(1) and keeps A(2) flying (R11 over-drained to 0).
// DO NOT add sync: every strengthening (R4 4-phase, R5 2-fat-phase, R12 t==8
// lgkm-drain restructure) regressed 10-30 us; this minimal-substitution form is
// the only schedule that beat R6's __syncthreads (163 -> 158).
__global__ __launch_bounds__(256, 2) void conv_mfma(
    const u16* __restrict__ Wmod, const u16* __restrict__ xt,
    float* __restrict__ out, int b0, int nb)
{
  const int id = blockIdx.x;
  const int bl = id % nb;                           // same batch -> same XCD (round robin)
  const int rest = id / nb;
  const int og = rest & 1, p_blk = rest >> 1;       // og: 256-row M chunk; p_blk: 128 px
  const int tid = threadIdx.x;
  const int lane = tid & 63, wave = tid >> 6;
  const int wm_off = (wave & 1) * 128, wn_off = (wave >> 1) * 64;
  const int l15 = lane & 15, quad = lane >> 4;

  __shared__ __align__(16) u16 As[3][8192];         // 3 x 16 KB A k-slices (tri-buffer)
  __shared__ __align__(16) u16 Bs[8448];            // [r4][col66][c32] = 16896 B

  const int y0 = p_blk * 2;
  const size_t xt_base = ((size_t)(bl * 16) * XT_CGELEMS) + (size_t)y0 * XT_ROWELEMS;
  const size_t w_base = (size_t)bl * WM_ELEMS + (size_t)og * (256 * 32);

  auto stage_b = [&](int cgi) {                     // 16896 B contiguous, async
    const char* g = (const char*)(xt + xt_base + (size_t)cgi * XT_CGELEMS);
    for (int r = wave; r < 16; r += 4)              // 4 GLDS/wave
      GLDS(g + r * 1024 + lane * 16, (char*)Bs + r * 1024);
    if (wave == 0 && lane < 32)                     // 512 B tail (wave0: 5th load)
      GLDS(g + 16384 + lane * 16, (char*)Bs + 16384);
  };
  auto stage_a = [&](int t, int cgi, int buf) {     // 16 KB contiguous, 4 GLDS/wave
    const char* g = (const char*)(Wmod + w_base + (size_t)(t * 16 + cgi) * 16384);
    for (int r = wave; r < 16; r += 4)
      GLDS(g + r * 1024 + lane * 16, (char*)As[buf] + r * 1024);
  };

  // loop-invariant swizzled fragment addresses (verified; conflicts = 0)
  int aoff[8];
#pragma unroll
  for (int mt = 0; mt < 8; ++mt) {
    int row = wm_off + mt * 16 + l15;               // local o-row; global o = og*256+row
    aoff[mt] = row * 32 + ((quad ^ ((row >> 1) & 3)) << 3);
  }
  int pr[4], pc[4];
#pragma unroll
  for (int nt = 0; nt < 4; ++nt) {
    int p = wn_off + nt * 16 + l15;
    pr[nt] = p >> 6; pc[nt] = p & 63;
  }

  floatx4 acc[8][4];
  const floatx4 zf = {0.f, 0.f, 0.f, 0.f};
#pragma unroll
  for (int mt = 0; mt < 8; ++mt)
#pragma unroll
    for (int nt = 0; nt < 4; ++nt) acc[mt][nt] = zf;

  // prologue: B(0) then A(s=0)->buf0 then A(s=1)->buf1; WAITVM(4) leaves A(1) in flight
  stage_b(0);
  stage_a(0, 0, 0);
  stage_a(1, 0, 1);
  WAITVM(4);
  __builtin_amdgcn_s_barrier();
  __builtin_amdgcn_sched_barrier(0);

#pragma unroll 1
  for (int cgi = 0; cgi < 16; ++cgi) {
#pragma unroll
    for (int t = 0; t < 9; ++t) {
      const int s = cgi * 9 + t;
      const int cur = t % 3;                        // s%3 == t%3 (9 ≡ 0 mod 3)
      // ---- top of step: counted drain + rendezvous (s==0 handled by prologue) ----
      if (s > 0) {
        if (t == 0 || s == 143) { WAITVM(0); }      // B(cg) newest / last A outstanding
        else                    { WAITVM(4); }      // A(s) done; A(s+1)/(A(2) at s==1) fly
        __builtin_amdgcn_s_barrier();
        __builtin_amdgcn_sched_barrier(0);
      }
      // ---- depth-2 A prefetch into buffer (s+2)%3 (write-after-read safe: its
      //      readers finished before barrier(s), which precedes this issue) ----
      if (s + 2 <= 143) {
        int t2 = t + 2, cg2 = cgi;
        if (t2 >= 9) { t2 -= 9; ++cg2; }
        stage_a(t2, cg2, (t + 2) % 3);
      }

      const int ky = t / 3, kx = t - ky * 3;
      s16x8 afr[8], bfr[4];
      const u16* Ab = As[cur];
#pragma unroll
      for (int nt = 0; nt < 4; ++nt) {              // B[n=lane&15][k=quad*8+j], swizzled
        int r = pr[nt] + ky, c = pc[nt] + kx;
        bfr[nt] = *(const s16x8*)&Bs[(r * 66 + c) * 32 + ((quad ^ ((c >> 1) & 3)) << 3)];
      }
#pragma unroll
      for (int mt = 0; mt < 8; ++mt)                // A[m=lane&15][k=quad*8+j], swizzled
        afr[mt] = *(const s16x8*)&Ab[aoff[mt]];
#pragma unroll
      for (int mt = 0; mt < 8; ++mt)
#pragma unroll
        for (int nt = 0; nt < 4; ++nt)
          acc[mt][nt] = __builtin_amdgcn_mfma_f32_16x16x32_bf16(
              afr[mt], bfr[nt], acc[mt][nt], 0, 0, 0);

      if (t == 8 && cgi < 15) {                     // cg boundary: restage Bs
        __builtin_amdgcn_s_barrier();               // all waves' Bs reads retired (lgkm
        __builtin_amdgcn_sched_barrier(0);          //  waits precede MFMAs precede here)
        stage_b(cgi + 1);                           // async; confirmed at next t==0 top
      }
    }
  }

  // epilogue: C/D layout col=lane&15, row=quad*4+reg (m89-verified)
  float* outp = out + ((size_t)(b0 + bl) * 512 + og * 256) * 4096 + p_blk * 128;
#pragma unroll
  for (int mt = 0; mt < 8; ++mt)
#pragma unroll
    for (int nt = 0; nt < 4; ++nt) {
      int n = wn_off + nt * 16 + l15;
#pragma unroll
      for (int r = 0; r < 4; ++r) {
        int m = wm_off + mt * 16 + quad * 4 + r;
        outp[(size_t)m * 4096 + n] = acc[mt][nt][r];
      }
    }
}

// ---------------- fallback: zero-workspace direct conv (known-PASS) ----------------
__global__ __launch_bounds__(256) void conv_direct(
    const float* __restrict__ fm, const float* __restrict__ style,
    const float* __restrict__ w, float* __restrict__ out)
{
  const int o = blockIdx.x, b = blockIdx.y, tid = threadIdx.x;
  __shared__ float swm[4608];
  __shared__ float red[4];
  const float gain = 0.014731391f;
  const float* wo = w + (size_t)o * 4608;
  const float* st = style + (size_t)b * 512;
  float ss = 0.f;
#pragma unroll
  for (int j = 0; j < 18; ++j) {
    int idx = j * 256 + tid;
    float v = wo[idx] * gain * st[idx / 9];
    swm[idx] = v;
    ss += v * v;
  }
#pragma unroll
  for (int off = 32; off > 0; off >>= 1) ss += __shfl_down(ss, off, 64);
  if ((tid & 63) == 0) red[tid >> 6] = ss;
  __syncthreads();
  const float sinv = rsqrtf(red[0] + red[1] + red[2] + red[3] + 1e-8f);

  const int y = tid >> 2, x0 = (tid & 3) * 16;
  float acc[16];
#pragma unroll
  for (int i = 0; i < 16; ++i) acc[i] = 0.f;
  const float* fb = fm + (size_t)b * 512 * 4096;
  for (int ci = 0; ci < 512; ++ci) {
    const float* fc = fb + (size_t)ci * 4096;
    const float* wr = swm + ci * 9;
#pragma unroll
    for (int ky = 0; ky < 3; ++ky) {
      int yy = y + ky - 1;
      if (yy < 0 || yy > 63) continue;
      const float* frow = fc + yy * 64;
#pragma unroll
      for (int kx = 0; kx < 3; ++kx) {
        float wv = wr[ky * 3 + kx];
#pragma unroll
        for (int i = 0; i < 16; ++i) {
          int xx = x0 + i + kx - 1;
          float xv = (xx >= 0 && xx < 64) ? frow[xx] : 0.f;
          acc[i] += wv * xv;
        }
      }
    }
  }
  float* op = out + ((size_t)b * 512 + o) * 4096 + y * 64 + x0;
#pragma unroll
  for (int i = 0; i < 16; ++i) op[i] = acc[i] * sinv;
}

extern "C" void kernel_launch(void* const* d_in, const int* in_sizes, int n_in,
                              void* d_out, int out_size, void* d_ws, size_t ws_size,
                              hipStream_t stream) {
  const float* fm = (const float*)d_in[0];     // (8,512,64,64) fp32
  const float* style = (const float*)d_in[1];  // (8,512) fp32
  const float* w = (const float*)d_in[2];      // (512,512,3,3) fp32
  float* out = (float*)d_out;                  // (8,512,64,64) fp32

  if (ws_size < XT_PB + WM_PB) {               // workspace too small: direct path
    conv_direct<<<dim3(512, 8), 256, 0, stream>>>(fm, style, w, out);
    return;
  }
  int nb = 8;
  while (nb > 1 && (size_t)nb * (XT_PB + WM_PB) > ws_size) nb >>= 1;

  u16* xt = (u16*)d_ws;
  u16* wmod = (u16*)((char*)d_ws + (size_t)nb * XT_PB);

  for (int b0 = 0; b0 < 8; b0 += nb) {
    prep_fused<<<dim3(1536 * nb), 256, 0, stream>>>(fm, w, style, xt, wmod, b0);
    conv_mfma<<<dim3(64 * nb), 256, 0, stream>>>(wmod, xt, out, b0, nb);
  }
}

// Round 14
// 261.636 us; speedup vs baseline: 1.0539x; 1.0338x over previous
//
#include <hip/hip_runtime.h>

typedef unsigned short u16;
typedef __attribute__((ext_vector_type(8))) short s16x8;   // 8 x bf16 frag (verified form)
typedef __attribute__((ext_vector_type(4))) float floatx4;

// xt (per batch): [cg=16][row=66][col=66][c32=32] bf16, spatial-padded NCHW32c,
// now holding x * style (style folded in). SWIZZLED: 16B slot ^= (col>>1)&3.
#define XT_ROWELEMS 2112                 // 66*32
#define XT_CGELEMS  139392               // 66*66*32
#define XT_PB       4460544ull           // 16*66*66*32*2 bytes per batch
// wb (batch-INDEPENDENT): [t=9][cg=16][o512=512][c32=32] bf16 = w*gain.
// SWIZZLED: within each 64B o-row, c32 index ^= ((o>>1)&3)<<3
#define WB_B        4718592ull           // 9*16*512*32*2 bytes
#define SIG_B       16384ull             // sigma_inv[8][512] fp32

// async global->LDS DMA, 16B per lane; lds dest = wave-uniform base + lane*16
#define GLDS(gp, lp) __builtin_amdgcn_global_load_lds(                      \
    (const __attribute__((address_space(1))) void*)(gp),                    \
    (__attribute__((address_space(3))) void*)(lp), 16, 0, 0)

__device__ __forceinline__ u16 f2bf(float f) {
  union { float f; unsigned u; } x; x.f = f;
  unsigned r = x.u + 0x7fffu + ((x.u >> 16) & 1u);
  return (u16)(r >> 16);
}

// ---------------- fused producer: transpose(x*style) + weight-convert + sigma ----------------
// grid 8704, 256 threads. Roles: bid%17==0 -> W (512 blocks, one per o);
// else T (8192 blocks: 1024 tiles x 8 batches). Interleaved for co-residency.
// W role: wb[o] = bf16(w[o]*gain) in conv layout (swizzled), PLUS
//   sigma_inv[b][o] = rsqrt(sum_{ci,t}(w*gain*style[b,ci])^2 + 1e-8) for all 8 b
//   (exact reference arithmetic, fp32). 8x less modulate-class work than before.
// T role: xt[b] = bf16(fm[b,ci] * style[b,ci]) (style folded into input; conv is
//   bilinear so conv(x*s, w*gain)*sinv == conv(x, w*gain*s*sinv) exactly).
__global__ __launch_bounds__(256) void prep_fused(
    const float* __restrict__ fm, const float* __restrict__ w,
    const float* __restrict__ style, u16* __restrict__ xt,
    u16* __restrict__ wb, float* __restrict__ sig)
{
  __shared__ __align__(16) char smraw[34944];     // W: 4608+4096+32 f32 | T: 64x40 u16
  const int bid = blockIdx.x;
  const int tid = threadIdx.x;
  const int g = bid / 17, rrole = bid - g * 17;

  if (rrole != 0) {
    // ---------- T role: transpose with style fold ----------
    u16* sm16 = (u16*)smraw;                      // [x=64][ci=32] pad 40
    const int ti = g * 16 + (rrole - 1);          // [0, 8192)
    const int y = ti & 63, cgi = (ti >> 6) & 15, bl = ti >> 10;
    const float* src = fm + (((size_t)bl * 512 + cgi * 32) * 64 + y) * 64;
    const float* stp = style + bl * 512 + cgi * 32;
    const int x4 = (tid & 15) * 4;
#pragma unroll
    for (int it = 0; it < 2; ++it) {
      int ci = (tid >> 4) + it * 16;
      float sval = stp[ci];
      float4 v = *(const float4*)&src[(size_t)ci * 4096 + x4];   // 16B/lane coalesced
      sm16[(x4 + 0) * 40 + ci] = f2bf(v.x * sval);
      sm16[(x4 + 1) * 40 + ci] = f2bf(v.y * sval);
      sm16[(x4 + 2) * 40 + ci] = f2bf(v.z * sval);
      sm16[(x4 + 3) * 40 + ci] = f2bf(v.w * sval);
    }

    u16* cgbase = xt + (size_t)(bl * 16 + cgi) * XT_CGELEMS;
    const uint4 z = {0u, 0u, 0u, 0u};
    u16* rowb = cgbase + (size_t)(y + 1) * XT_ROWELEMS;
    if (tid < 4)              ((uint4*)rowb)[tid] = z;                  // col 0
    else if (tid < 8)         ((uint4*)(rowb + 65 * 32))[tid - 4] = z;  // col 65
    if (y == 0)  for (int i = tid; i < 264; i += 256) ((uint4*)cgbase)[i] = z;
    if (y == 63) for (int i = tid; i < 264; i += 256) ((uint4*)(cgbase + 65 * XT_ROWELEMS))[i] = z;

    __syncthreads();
    const int x = tid >> 2;
    uint4 u = *(const uint4*)&sm16[x * 40 + (tid & 3) * 8];       // one ds_read_b128
    const int col = 1 + x;
    const int slot = (tid & 3) ^ ((col >> 1) & 3);                // pre-swizzle
    ((uint4*)rowb)[col * 4 + slot] = u;
  } else {
    // ---------- W role: one o; wb = bf16(w*gain); sigma_inv for 8 batches ----------
    float* sv = (float*)smraw;                    // 4608: w[o]*gain, idx = ci*9 + t
    float* s2 = sv + 4608;                        // 4096: style^2 for 8 batches
    float* red = s2 + 4096;                       // 32: per-wave partials x 8 b
    const int o = g;
    const float gain = 0.014731391f;              // 1/sqrt(512*9)
    const float* wo = w + (size_t)o * 4608;
    for (int i = tid; i < 4096; i += 256) { float s = style[i]; s2[i] = s * s; }
    __syncthreads();

    float ss[8];
#pragma unroll
    for (int b = 0; b < 8; ++b) ss[b] = 0.f;
#pragma unroll
    for (int j = 0; j < 5; ++j) {                 // 1152 float4 slots over 256 thr
      int s4 = j * 256 + tid;
      if (s4 < 1152) {
        float4 v = *(const float4*)&wo[s4 * 4];   // 16B/lane coalesced
        int i0 = s4 * 4;
        int c0 = i0 / 9, rem = i0 - c0 * 9;       // ci of elem 0
        int ci1 = c0 + (rem + 1 >= 9), ci2 = c0 + (rem + 2 >= 9), ci3 = c0 + (rem + 3 >= 9);
        floatx4 wv = {v.x * gain, v.y * gain, v.z * gain, v.w * gain};
        ((floatx4*)sv)[s4] = wv;                  // ds_write_b128
        float q0 = wv[0] * wv[0], q1 = wv[1] * wv[1];
        float q2 = wv[2] * wv[2], q3 = wv[3] * wv[3];
#pragma unroll
        for (int b = 0; b < 8; ++b) {
          const float* sb = s2 + b * 512;
          ss[b] += q0 * sb[c0] + q1 * sb[ci1] + q2 * sb[ci2] + q3 * sb[ci3];
        }
      }
    }
    const int lane = tid & 63, wave = tid >> 6;
#pragma unroll
    for (int b = 0; b < 8; ++b) {
#pragma unroll
      for (int off = 32; off > 0; off >>= 1) ss[b] += __shfl_down(ss[b], off, 64);
    }
    if (lane == 0)
#pragma unroll
      for (int b = 0; b < 8; ++b) red[wave * 8 + b] = ss[b];
    __syncthreads();
    if (tid < 8) {
      float t8 = red[tid] + red[8 + tid] + red[16 + tid] + red[24 + tid];
      sig[tid * 512 + o] = rsqrtf(t8 + 1e-8f);    // sigma_inv[b][o]
    }

    // wb store: [t][cg][o][c32], swizzled o-row; NO style, NO sinv (hoisted out)
    const int axor = ((o >> 1) & 3) << 3;
    u16* base = wb + (size_t)o * 32;
    const int c0 = tid * 2;                       // even -> XOR keeps pair adjacent
    const int pos = (c0 & 31) ^ axor;             // even (axor has no bit0)
#pragma unroll
    for (int t = 0; t < 9; ++t) {                 // 9 paired u32 stores
      unsigned lo = f2bf(sv[c0 * 9 + t]);
      unsigned hi = f2bf(sv[(c0 + 1) * 9 + t]);
      *(unsigned*)(base + ((size_t)(t * 16 + (c0 >> 5))) * 16384 + pos) = lo | (hi << 16);
    }
  }
}

// ---------------- conv: R6-verified body (best total 267.36) + sigma epilogue ----------------
// 256x128 C tile, 256 threads = 4 waves, wave tile 128x64, 16x16x32 MFMA, plain
// __syncthreads discipline (every counted-vmcnt/phase variant R4/R5/R11/R12/R13
// measured equal-or-worse within the +-6us cross-session noise). Changes vs R6:
// (1) A base has no batch term (wb is batch-independent, 4.5 MB -> L2-resident);
// (2) epilogue multiplies acc by sigma_inv[bl][og*256+m] (LDS-preloaded).
__global__ __launch_bounds__(256, 2) void conv_mfma(
    const u16* __restrict__ wb, const u16* __restrict__ xt,
    const float* __restrict__ sig, float* __restrict__ out)
{
  const int id = blockIdx.x;
  const int bl = id & 7;                            // same batch -> same XCD (round robin)
  const int rest = id >> 3;
  const int og = rest & 1, p_blk = rest >> 1;       // og: 256-row M chunk; p_blk: 128 px
  const int tid = threadIdx.x;
  const int lane = tid & 63, wave = tid >> 6;
  const int wm_off = (wave & 1) * 128, wn_off = (wave >> 1) * 64;
  const int l15 = lane & 15, quad = lane >> 4;

  __shared__ __align__(16) u16 As[2][8192];         // 2 x 16 KB A k-slices (256 rows x 32)
  __shared__ __align__(16) u16 Bs[8448];            // [r4][col66][c32] = 16896 B
  __shared__ float sig_l[256];

  const int y0 = p_blk * 2;
  const size_t xt_base = ((size_t)(bl * 16) * XT_CGELEMS) + (size_t)y0 * XT_ROWELEMS;
  const size_t w_base = (size_t)og * (256 * 32);    // batch-independent

  auto stage_b = [&](int cgi) {                     // 16896 B contiguous, async
    const char* g = (const char*)(xt + xt_base + (size_t)cgi * XT_CGELEMS);
    for (int r = wave; r < 16; r += 4)
      GLDS(g + r * 1024 + lane * 16, (char*)Bs + r * 1024);
    if (wave == 0 && lane < 32)                     // 512 B tail
      GLDS(g + 16384 + lane * 16, (char*)Bs + 16384);
  };
  auto stage_a = [&](int t, int cgi, int buf) {     // 16 KB contiguous, async (4 GLDS/wave)
    const char* g = (const char*)(wb + w_base + (size_t)(t * 16 + cgi) * 16384);
    for (int r = wave; r < 16; r += 4)
      GLDS(g + r * 1024 + lane * 16, (char*)As[buf] + r * 1024);
  };

  // loop-invariant swizzled fragment addresses (verified; conflicts = 0)
  int aoff[8];
#pragma unroll
  for (int mt = 0; mt < 8; ++mt) {
    int row = wm_off + mt * 16 + l15;               // local o-row; global o = og*256+row
    aoff[mt] = row * 32 + ((quad ^ ((row >> 1) & 3)) << 3);
  }
  int pr[4], pc[4];
#pragma unroll
  for (int nt = 0; nt < 4; ++nt) {
    int p = wn_off + nt * 16 + l15;
    pr[nt] = p >> 6; pc[nt] = p & 63;
  }

  floatx4 acc[8][4];
  const floatx4 zf = {0.f, 0.f, 0.f, 0.f};
#pragma unroll
  for (int mt = 0; mt < 8; ++mt)
#pragma unroll
    for (int nt = 0; nt < 4; ++nt) acc[mt][nt] = zf;

  stage_b(0);
  stage_a(0, 0, 0);
  __syncthreads();                                  // vmcnt drain -> data visible

#pragma unroll 1
  for (int cgi = 0; cgi < 16; ++cgi) {
#pragma unroll 1
    for (int t = 0; t < 9; ++t) {
      const int cur = (cgi * 9 + t) & 1, nxt = cur ^ 1;
      const bool last = (cgi == 15 && t == 8);
      const bool cgb = (t == 8 && cgi < 15);        // cg boundary
      if (!last) stage_a(t < 8 ? t + 1 : 0, t < 8 ? cgi : cgi + 1, nxt);  // async prefetch

      const int ky = t / 3, kx = t - ky * 3;
      s16x8 afr[8], bfr[4];
      const u16* Ab = As[cur];
#pragma unroll
      for (int nt = 0; nt < 4; ++nt) {              // B[n=lane&15][k=quad*8+j], swizzled
        int r = pr[nt] + ky, c = pc[nt] + kx;
        bfr[nt] = *(const s16x8*)&Bs[(r * 66 + c) * 32 + ((quad ^ ((c >> 1) & 3)) << 3)];
      }
#pragma unroll
      for (int mt = 0; mt < 8; ++mt)                // A[m=lane&15][k=quad*8+j], swizzled
        afr[mt] = *(const s16x8*)&Ab[aoff[mt]];
#pragma unroll
      for (int mt = 0; mt < 8; ++mt)
#pragma unroll
        for (int nt = 0; nt < 4; ++nt)
          acc[mt][nt] = __builtin_amdgcn_mfma_f32_16x16x32_bf16(
              afr[mt], bfr[nt], acc[mt][nt], 0, 0, 0);

      if (cgb) {
        __syncthreads();                            // all waves done reading Bs
        stage_b(cgi + 1);                           // async restage
      }
      __syncthreads();                              // drains DMA; LDS visible
    }
  }

  // sigma preload: rows og*256 .. og*256+255 of batch bl
  sig_l[tid] = sig[bl * 512 + og * 256 + tid];
  __syncthreads();

  // epilogue: C/D layout col=lane&15, row=quad*4+reg (m89-verified); apply sigma_inv
  float* outp = out + ((size_t)bl * 512 + og * 256) * 4096 + p_blk * 128;
#pragma unroll
  for (int mt = 0; mt < 8; ++mt)
#pragma unroll
    for (int nt = 0; nt < 4; ++nt) {
      int n = wn_off + nt * 16 + l15;
#pragma unroll
      for (int r = 0; r < 4; ++r) {
        int m = wm_off + mt * 16 + quad * 4 + r;
        outp[(size_t)m * 4096 + n] = acc[mt][nt][r] * sig_l[m];
      }
    }
}

// ---------------- fallback: zero-workspace direct conv (known-PASS) ----------------
__global__ __launch_bounds__(256) void conv_direct(
    const float* __restrict__ fm, const float* __restrict__ style,
    const float* __restrict__ w, float* __restrict__ out)
{
  const int o = blockIdx.x, b = blockIdx.y, tid = threadIdx.x;
  __shared__ float swm[4608];
  __shared__ float red[4];
  const float gain = 0.014731391f;
  const float* wo = w + (size_t)o * 4608;
  const float* st = style + (size_t)b * 512;
  float ss = 0.f;
#pragma unroll
  for (int j = 0; j < 18; ++j) {
    int idx = j * 256 + tid;
    float v = wo[idx] * gain * st[idx / 9];
    swm[idx] = v;
    ss += v * v;
  }
#pragma unroll
  for (int off = 32; off > 0; off >>= 1) ss += __shfl_down(ss, off, 64);
  if ((tid & 63) == 0) red[tid >> 6] = ss;
  __syncthreads();
  const float sinv = rsqrtf(red[0] + red[1] + red[2] + red[3] + 1e-8f);

  const int y = tid >> 2, x0 = (tid & 3) * 16;
  float acc[16];
#pragma unroll
  for (int i = 0; i < 16; ++i) acc[i] = 0.f;
  const float* fb = fm + (size_t)b * 512 * 4096;
  for (int ci = 0; ci < 512; ++ci) {
    const float* fc = fb + (size_t)ci * 4096;
    const float* wr = swm + ci * 9;
#pragma unroll
    for (int ky = 0; ky < 3; ++ky) {
      int yy = y + ky - 1;
      if (yy < 0 || yy > 63) continue;
      const float* frow = fc + yy * 64;
#pragma unroll
      for (int kx = 0; kx < 3; ++kx) {
        float wv = wr[ky * 3 + kx];
#pragma unroll
        for (int i = 0; i < 16; ++i) {
          int xx = x0 + i + kx - 1;
          float xv = (xx >= 0 && xx < 64) ? frow[xx] : 0.f;
          acc[i] += wv * xv;
        }
      }
    }
  }
  float* op = out + ((size_t)b * 512 + o) * 4096 + y * 64 + x0;
#pragma unroll
  for (int i = 0; i < 16; ++i) op[i] = acc[i] * sinv;
}

extern "C" void kernel_launch(void* const* d_in, const int* in_sizes, int n_in,
                              void* d_out, int out_size, void* d_ws, size_t ws_size,
                              hipStream_t stream) {
  const float* fm = (const float*)d_in[0];     // (8,512,64,64) fp32
  const float* style = (const float*)d_in[1];  // (8,512) fp32
  const float* w = (const float*)d_in[2];      // (512,512,3,3) fp32
  float* out = (float*)d_out;                  // (8,512,64,64) fp32

  const size_t need = 8ull * XT_PB + WB_B + SIG_B;   // 40.4 MB (< old 73.4 MB req)
  if (ws_size < need) {                        // workspace too small: direct path
    conv_direct<<<dim3(512, 8), 256, 0, stream>>>(fm, style, w, out);
    return;
  }

  u16* xt = (u16*)d_ws;
  u16* wb = (u16*)((char*)d_ws + 8ull * XT_PB);
  float* sig = (float*)((char*)wb + WB_B);

  prep_fused<<<dim3(8704), 256, 0, stream>>>(fm, w, style, xt, wb, sig);
  conv_mfma<<<dim3(512), 256, 0, stream>>>(wb, xt, sig, out);
}